// Round 11
// baseline (800.843 us; speedup 1.0000x reference)
//
#include <hip/hip_runtime.h>
#include <math.h>

#define LN_EPS 1e-3f
#define NSLOT 64

typedef __attribute__((ext_vector_type(8))) short short8;
typedef __attribute__((ext_vector_type(4))) float floatx4;

__device__ __forceinline__ float silu_f(float x) { return x / (1.f + expf(-x)); }

__device__ __forceinline__ int mism1(float a, float s) {
    unsigned ua = __float_as_uint(a);
    unsigned ub = __float_as_uint(a + s);
    return (int)((ua ^ ub) >> 31);
}

__device__ __forceinline__ short f2bf(float f) {
    unsigned u = __float_as_uint(f);
    unsigned r = (u + 0x7FFFu + ((u >> 16) & 1u)) >> 16;
    return (short)r;
}

// Striped grid barrier: 64 counters on separate 64B lines; 512 blocks -> 8
// serialized RMWs/line (parallel across lines). Monotone targets, no reset.
// Safe: grid(512) == residency capacity (2 blocks/CU x 256 CU, LB(256,2)).
__device__ __forceinline__ void gbar(unsigned* slots, unsigned target) {
    __syncthreads();
    int tid = threadIdx.x;
    if (tid == 0)
        __hip_atomic_fetch_add(slots + (blockIdx.x & (NSLOT - 1)) * 16, 1u,
                               __ATOMIC_ACQ_REL, __HIP_MEMORY_SCOPE_AGENT);
    if (tid < NSLOT) {
        while (__hip_atomic_load(slots + tid * 16, __ATOMIC_ACQUIRE,
                                 __HIP_MEMORY_SCOPE_AGENT) < target)
            __builtin_amdgcn_s_sleep(2);
    }
    __syncthreads();
}

// ===== One mega-kernel: prep -> conv1 -> conv2 -> cnt -> out =====
// grid = 512 blocks x 256 threads (2 blocks/CU co-resident).
__global__ __launch_bounds__(256, 2) void k_mega(
    const float* __restrict__ values,   // (4,1920,512)
    const float* __restrict__ symbols,  // (1920,512)
    const float* __restrict__ w1,       // (5,512,128)
    const float* __restrict__ w2,       // (3,128,1024)
    const float* __restrict__ b1,
    const float* __restrict__ g1,
    const float* __restrict__ bt1,
    const float* __restrict__ b2,
    const float* __restrict__ g2,
    const float* __restrict__ bt2,
    short* __restrict__ w1s,            // ws: 327,680 bf16
    short* __restrict__ w2s,            // ws: 393,216 bf16
    short* __restrict__ h1,             // ws: (3200,128) bf16
    int*   __restrict__ cnt2,           // ws: (4,64,2,2,128) int
    float* __restrict__ vp,             // out+512K: (512,1024)
    float* __restrict__ sp,             // ws: (128,1024)
    float* __restrict__ O,              // out: (4,128,1024)
    unsigned* __restrict__ slots)       // ws: 64 x 16 uints (memset to 0)
{
    __shared__ __align__(16) char smem[21760];

    int blk  = blockIdx.x;
    int tid  = threadIdx.x;
    int lane = tid & 63, w = tid >> 6;
    int quad = lane >> 4, mrow = lane & 15;

    // ---------------- phase 0: weight swizzle (all 512 blocks)
    for (int t = blk * 256 + tid; t < 720896; t += 131072) {
        if (t < 327680) {
            int j    = t & 7;
            int ln   = (t >> 3) & 63;
            int nt   = (t >> 9) & 7;
            int ks   = (t >> 12) % 10;
            int kc   = t / 40960;
            int kw = ks >> 1;
            int ci = kc * 64 + (ks & 1) * 32 + ((ln >> 4) & 3) * 8 + j;
            int n  = nt * 16 + (ln & 15);
            w1s[t] = f2bf(w1[((size_t)(kw * 512 + ci)) * 128 + n]);
        } else {
            int q = t - 327680;
            int j    = q & 7;
            int ln   = (q >> 3) & 63;
            int nt   = (q >> 9) & 63;
            int ks   = q >> 15;                      // 0..11
            int k  = ks * 32 + ((ln >> 4) & 3) * 8 + j;
            int kw = k >> 7;
            int ci = k & 127;
            int n  = nt * 16 + (ln & 15);
            w2s[q] = f2bf(w2[((size_t)(kw * 128 + ci)) * 1024 + n]);
        }
    }
    gbar(slots, 8);

    // ---------------- phase 1: conv1 MFMA + bias + LN1(128) + SiLU -> h1 (blk<200)
    if (blk < 200) {
        short* xs   = (short*)smem;          // 50*72 shorts
        float* red1 = (float*)(smem + 7200); // 4*4*4*2 floats

        int seq = blk / 40;
        int tl  = blk % 40;
        const float* x = (seq < 4) ? (values + (size_t)seq * 1920 * 512) : symbols;
        int p0 = 3 * (tl * 16) - 1;

        floatx4 acc[2];
        acc[0] = (floatx4){0.f, 0.f, 0.f, 0.f};
        acc[1] = (floatx4){0.f, 0.f, 0.f, 0.f};

        for (int kc = 0; kc < 8; kc++) {
            __syncthreads();
            for (int idx = tid; idx < 50 * 16; idx += 256) {
                int r = idx >> 4, g = idx & 15;
                int gp = p0 + r;
                float4 v = make_float4(0.f, 0.f, 0.f, 0.f);
                if (gp >= 0 && gp < 1920)
                    v = *(const float4*)(x + (size_t)gp * 512 + kc * 64 + 4 * g);
                short* d = xs + r * 72 + 4 * g;
                d[0] = f2bf(v.x); d[1] = f2bf(v.y); d[2] = f2bf(v.z); d[3] = f2bf(v.w);
            }
            __syncthreads();

            #pragma unroll
            for (int ks = 0; ks < 10; ks++) {
                int kw  = ks >> 1;
                int ci0 = (ks & 1) * 32;
                short8 a = *(const short8*)(xs + (3 * mrow + kw) * 72 + ci0 + quad * 8);
                #pragma unroll
                for (int ni = 0; ni < 2; ni++) {
                    short8 b = *(const short8*)(w1s +
                        ((((size_t)kc * 10 + ks) * 8 + (w * 2 + ni)) * 64 + lane) * 8);
                    acc[ni] = __builtin_amdgcn_mfma_f32_16x16x32_bf16(a, b, acc[ni], 0, 0, 0);
                }
            }
        }

        float b1v[2], g1v[2], btv[2];
        #pragma unroll
        for (int ni = 0; ni < 2; ni++) {
            int co = w * 32 + ni * 16 + mrow;
            b1v[ni] = b1[co]; g1v[ni] = g1[co]; btv[ni] = bt1[co];
        }

        float s1[4] = {0.f, 0.f, 0.f, 0.f}, s2[4] = {0.f, 0.f, 0.f, 0.f};
        #pragma unroll
        for (int ni = 0; ni < 2; ni++)
            #pragma unroll
            for (int r = 0; r < 4; r++) {
                float v = acc[ni][r] + b1v[ni];
                acc[ni][r] = v;
                s1[r] += v; s2[r] += v * v;
            }
        #pragma unroll
        for (int m = 8; m >= 1; m >>= 1) {
            #pragma unroll
            for (int r = 0; r < 4; r++) {
                s1[r] += __shfl_xor(s1[r], m, 64);
                s2[r] += __shfl_xor(s2[r], m, 64);
            }
        }
        if (mrow == 0) {
            #pragma unroll
            for (int r = 0; r < 4; r++) {
                red1[(((w * 4 + quad) * 4) + r) * 2 + 0] = s1[r];
                red1[(((w * 4 + quad) * 4) + r) * 2 + 1] = s2[r];
            }
        }
        __syncthreads();

        #pragma unroll
        for (int r = 0; r < 4; r++) {
            float S1 = 0.f, S2 = 0.f;
            #pragma unroll
            for (int ww = 0; ww < 4; ww++) {
                S1 += red1[(((ww * 4 + quad) * 4) + r) * 2 + 0];
                S2 += red1[(((ww * 4 + quad) * 4) + r) * 2 + 1];
            }
            float mean = S1 * (1.f / 128.f);
            float var  = S2 * (1.f / 128.f) - mean * mean;
            float rs   = rsqrtf(var + LN_EPS);
            int row = seq * 640 + tl * 16 + quad * 4 + r;
            #pragma unroll
            for (int ni = 0; ni < 2; ni++) {
                float o = silu_f((acc[ni][r] - mean) * rs * g1v[ni] + btv[ni]);
                h1[(size_t)row * 128 + w * 32 + ni * 16 + mrow] = f2bf(o);
            }
        }
    }
    gbar(slots, 16);

    // ---------------- phase 2: conv2 MFMA + LN2(1024) + SiLU -> vp/sp (blk<40)
    if (blk < 40) {
        short* xa   = (short*)smem;            // 78*136 shorts
        float* red2 = (float*)(smem + 21216);  // 4*4*4*2 floats

        int pos0 = blk * 16;
        int seq  = pos0 >> 7;
        int lcl0 = pos0 & 127;
        int row0 = seq * 640 + 5 * lcl0;

        for (int idx = tid; idx < 78 * 16; idx += 256) {
            int r = idx >> 4, g = idx & 15;
            *(short8*)(xa + r * 136 + g * 8) =
                *(const short8*)(h1 + (size_t)(row0 + r) * 128 + g * 8);
        }
        __syncthreads();

        floatx4 acc[16];
        #pragma unroll
        for (int nt = 0; nt < 16; nt++) acc[nt] = (floatx4){0.f, 0.f, 0.f, 0.f};

        #pragma unroll 3
        for (int ks = 0; ks < 12; ks++) {
            int kw  = ks >> 2;
            int ci0 = (ks & 3) * 32;
            short8 a = *(const short8*)(xa + (5 * mrow + kw) * 136 + ci0 + quad * 8);
            #pragma unroll
            for (int nt = 0; nt < 16; nt++) {
                short8 b = *(const short8*)(w2s +
                    (((size_t)ks * 64 + w * 16 + nt) * 64 + lane) * 8);
                acc[nt] = __builtin_amdgcn_mfma_f32_16x16x32_bf16(a, b, acc[nt], 0, 0, 0);
            }
        }

        float b2v[16], g2v[16], btv[16];
        #pragma unroll
        for (int nt = 0; nt < 16; nt++) {
            int co = w * 256 + nt * 16 + mrow;
            b2v[nt] = b2[co]; g2v[nt] = g2[co]; btv[nt] = bt2[co];
        }

        float s1[4] = {0.f, 0.f, 0.f, 0.f}, s2[4] = {0.f, 0.f, 0.f, 0.f};
        #pragma unroll
        for (int nt = 0; nt < 16; nt++)
            #pragma unroll
            for (int r = 0; r < 4; r++) {
                float v = acc[nt][r] + b2v[nt];
                acc[nt][r] = v;
                s1[r] += v; s2[r] += v * v;
            }
        #pragma unroll
        for (int m = 8; m >= 1; m >>= 1) {
            #pragma unroll
            for (int r = 0; r < 4; r++) {
                s1[r] += __shfl_xor(s1[r], m, 64);
                s2[r] += __shfl_xor(s2[r], m, 64);
            }
        }
        if (mrow == 0) {
            #pragma unroll
            for (int r = 0; r < 4; r++) {
                red2[(((w * 4 + quad) * 4) + r) * 2 + 0] = s1[r];
                red2[(((w * 4 + quad) * 4) + r) * 2 + 1] = s2[r];
            }
        }
        __syncthreads();

        float mean[4], rs[4];
        #pragma unroll
        for (int r = 0; r < 4; r++) {
            float S1 = 0.f, S2 = 0.f;
            #pragma unroll
            for (int ww = 0; ww < 4; ww++) {
                S1 += red2[(((ww * 4 + quad) * 4) + r) * 2 + 0];
                S2 += red2[(((ww * 4 + quad) * 4) + r) * 2 + 1];
            }
            mean[r] = S1 * (1.f / 1024.f);
            float var = S2 * (1.f / 1024.f) - mean[r] * mean[r];
            rs[r] = rsqrtf(var + LN_EPS);
        }

        float* obase = (pos0 < 512) ? (vp + (size_t)pos0 * 1024)
                                    : (sp + (size_t)(pos0 - 512) * 1024);
        #pragma unroll
        for (int nt = 0; nt < 16; nt++) {
            int co = w * 256 + nt * 16 + mrow;
            #pragma unroll
            for (int r = 0; r < 4; r++) {
                float o = silu_f((acc[nt][r] - mean[r]) * rs[r] * g2v[nt] + btv[nt]);
                obase[((size_t)(quad * 4 + r)) * 1024 + co] = o;
            }
        }
    }
    gbar(slots, 24);

    // ---------------- phase 3: mismatch counts (all 512 blocks)
    {
        int half = blk & 1;
        int jp   = (blk >> 1) & 63;
        int b    = blk >> 7;
        int j0   = jp * 2;
        int i = tid & 127, sub = tid >> 7;
        int d0 = half * 512 + sub * 256;

        const float* vrow = vp + ((size_t)(b * 128 + i)) * 1024 + d0;
        const float* s0r  = sp + (size_t)j0 * 1024 + d0;
        const float* s1r  = s0r + 1024;

        int m0 = 0, m1 = 0;
        #pragma unroll 8
        for (int k = 0; k < 64; k++) {
            float4 v  = *(const float4*)(vrow + 4 * k);
            float4 s0 = *(const float4*)(s0r + 4 * k);
            float4 s1 = *(const float4*)(s1r + 4 * k);
            m0 += mism1(v.x, s0.x) + mism1(v.y, s0.y) + mism1(v.z, s0.z) + mism1(v.w, s0.w);
            m1 += mism1(v.x, s1.x) + mism1(v.y, s1.y) + mism1(v.z, s1.z) + mism1(v.w, s1.w);
        }

        int* cc = (int*)smem;  // [2][128][2]
        cc[(sub * 128 + i) * 2 + 0] = m0;
        cc[(sub * 128 + i) * 2 + 1] = m1;
        __syncthreads();

        if (tid < 128) {
            int base = (((b * 64 + jp) * 2 + 0) * 2 + half) * 128;
            cnt2[base + tid]       = cc[tid * 2 + 0] + cc[(128 + tid) * 2 + 0];
            cnt2[base + 256 + tid] = cc[tid * 2 + 1] + cc[(128 + tid) * 2 + 1];
        }
    }
    gbar(slots, 32);

    // ---------------- phase 4: softmax + einsum + SiLU (all 512 blocks)
    {
        int half = blk & 1;
        int jp   = (blk >> 1) & 63;
        int b    = blk >> 7;
        int j0   = jp * 2;

        float* sc   = (float*)smem;           // [2][128]
        float* redm = (float*)(smem + 1024);  // [2][2]
        float* reds = (float*)(smem + 1056);  // [2][2]

        {
            int jj = w >> 1, ih = w & 1;
            int i = ih * 64 + lane;
            int c = cnt2[((((b * 64 + jp) * 2 + jj) * 2 + 0) * 128) + i]
                  + cnt2[((((b * 64 + jp) * 2 + jj) * 2 + 1) * 128) + i];
            float S = 1.f - (float)c * (2.f / 1024.f);
            float mx = S;
            #pragma unroll
            for (int m = 32; m >= 1; m >>= 1) mx = fmaxf(mx, __shfl_xor(mx, m, 64));
            if (lane == 0) redm[jj * 2 + ih] = mx;
            __syncthreads();
            float MX = fmaxf(redm[jj * 2 + 0], redm[jj * 2 + 1]);
            float e = expf(S - MX);
            float sm = e;
            #pragma unroll
            for (int m = 32; m >= 1; m >>= 1) sm += __shfl_xor(sm, m, 64);
            if (lane == 0) reds[jj * 2 + ih] = sm;
            sc[jj * 128 + i] = e;
            __syncthreads();
        }

        int jj   = tid >> 7;
        int dloc = tid & 127;
        int dd   = half * 512 + 4 * dloc;
        int j    = j0 + jj;
        float inv = 1.f / (reds[jj * 2 + 0] + reds[jj * 2 + 1]);

        const float* vpb = vp + (size_t)b * 131072;
        float4 ao = make_float4(0.f, 0.f, 0.f, 0.f);
        #pragma unroll 4
        for (int i = 0; i < 128; i++) {
            float4 v = *(const float4*)(vpb + (size_t)i * 1024 + dd);
            float f = sc[jj * 128 + i];
            ao.x += f * v.x; ao.y += f * v.y; ao.z += f * v.z; ao.w += f * v.w;
        }
        float4 s = *(const float4*)(sp + (size_t)j * 1024 + dd);
        float4 o;
        o.x = silu_f(ao.x * inv * s.x);
        o.y = silu_f(ao.y * inv * s.y);
        o.z = silu_f(ao.z * inv * s.z);
        o.w = silu_f(ao.w * inv * s.w);
        *(float4*)(O + ((size_t)b * 128 + j) * 1024 + dd) = o;
    }
}

extern "C" void kernel_launch(void* const* d_in, const int* in_sizes, int n_in,
                              void* d_out, int out_size, void* d_ws, size_t ws_size,
                              hipStream_t stream) {
    const float* values  = (const float*)d_in[0];
    const float* symbols = (const float*)d_in[1];
    const float* conv1_w = (const float*)d_in[2];
    const float* conv1_b = (const float*)d_in[3];
    const float* ln1_g   = (const float*)d_in[4];
    const float* ln1_b   = (const float*)d_in[5];
    const float* conv2_w = (const float*)d_in[6];
    const float* conv2_b = (const float*)d_in[7];
    const float* ln2_g   = (const float*)d_in[8];
    const float* ln2_b   = (const float*)d_in[9];

    float* out = (float*)d_out;
    float* O   = out;                       // (4,128,1024)
    float* vp  = out + 4 * 128 * 1024;      // (4,128,1024)

    float*    sp    = (float*)d_ws;               // (128,1024) f32
    short*    h1    = (short*)(sp + 128 * 1024);  // (3200,128) bf16
    short*    w1s   = h1 + 3200 * 128;            // 327,680
    short*    w2s   = w1s + 327680;               // 393,216
    int*      cnt2  = (int*)(w2s + 393216);       // 131,072 ints
    unsigned* slots = (unsigned*)(cnt2 + 131072); // 64 x 16 uints

    hipMemsetAsync(slots, 0, NSLOT * 16 * sizeof(unsigned), stream);
    k_mega<<<512, 256, 0, stream>>>(values, symbols, conv1_w, conv2_w,
                                    conv1_b, ln1_g, ln1_b,
                                    conv2_b, ln2_g, ln2_b,
                                    w1s, w2s, h1, cnt2, vp, sp, O, slots);
}

// Round 12
// 186.574 us; speedup vs baseline: 4.2924x; 4.2924x over previous
//
#include <hip/hip_runtime.h>
#include <math.h>

#define LN_EPS 1e-3f

typedef __attribute__((ext_vector_type(8))) short short8;
typedef __attribute__((ext_vector_type(4))) float floatx4;

__device__ __forceinline__ float silu_f(float x) { return x / (1.f + expf(-x)); }

__device__ __forceinline__ int mism1(float a, float s) {
    unsigned ua = __float_as_uint(a);
    unsigned ub = __float_as_uint(a + s);
    return (int)((ua ^ ub) >> 31);
}

__device__ __forceinline__ short f2bf(float f) {
    unsigned u = __float_as_uint(f);
    unsigned r = (u + 0x7FFFu + ((u >> 16) & 1u)) >> 16;
    return (short)r;
}

// ---------------- Kernel 0: swizzle conv1 + conv2 weights into B-fragment bf16
// w1s[kc(8)][ks(10)][nt(8)][lane(64)][j(8)]  (327,680)
// w2s[ks(12)][nt(64)][lane(64)][j(8)]        (393,216)
__global__ __launch_bounds__(256) void k_prep(
    const float* __restrict__ w1,   // (5,512,128)
    const float* __restrict__ w2,   // (3,128,1024)
    short* __restrict__ w1s,
    short* __restrict__ w2s)
{
    int tid = blockIdx.x * 256 + threadIdx.x;
    if (tid < 327680) {
        int j    = tid & 7;
        int lane = (tid >> 3) & 63;
        int nt   = (tid >> 9) & 7;
        int ks   = (tid >> 12) % 10;
        int kc   = tid / 40960;
        int kw = ks >> 1;
        int ci = kc * 64 + (ks & 1) * 32 + ((lane >> 4) & 3) * 8 + j;
        int n  = nt * 16 + (lane & 15);
        w1s[tid] = f2bf(w1[((size_t)(kw * 512 + ci)) * 128 + n]);
    } else {
        int t = tid - 327680;
        if (t < 393216) {
            int j    = t & 7;
            int lane = (t >> 3) & 63;
            int nt   = (t >> 9) & 63;
            int ks   = t >> 15;                 // 0..11
            int k  = ks * 32 + ((lane >> 4) & 3) * 8 + j;   // 0..383
            int kw = k >> 7;
            int ci = k & 127;
            int n  = nt * 16 + (lane & 15);
            w2s[t] = f2bf(w2[((size_t)(kw * 128 + ci)) * 1024 + n]);
        }
    }
}

// ---------------- Kernel 1: conv1 MFMA + bias + LN1(128) + SiLU -> h1 bf16
// grid = 200 blocks (16 pos each), 512 threads (8 waves, 1 n-tile of 16 co each).
__global__ __launch_bounds__(512) void k_conv1m(
    const float* __restrict__ values,   // (4,1920,512)
    const float* __restrict__ symbols,  // (1920,512)
    const short* __restrict__ w1s,
    const float* __restrict__ b1,
    const float* __restrict__ g1,
    const float* __restrict__ bt1,
    short* __restrict__ h1)             // (3200,128) bf16
{
    int mt  = blockIdx.x;               // 0..199
    int seq = mt / 40;
    int tl  = mt % 40;
    const float* x = (seq < 4) ? (values + (size_t)seq * 1920 * 512) : symbols;
    int p0 = 3 * (tl * 16) - 1;

    __shared__ short xs[50 * 72];            // 7200 B
    __shared__ float red[8][4][4][2];        // 1 KB

    int tid  = threadIdx.x;
    int lane = tid & 63, w = tid >> 6;       // w = 0..7 (= n-tile)
    int quad = lane >> 4, mrow = lane & 15;

    floatx4 acc = (floatx4){0.f, 0.f, 0.f, 0.f};

    for (int kc = 0; kc < 8; kc++) {
        __syncthreads();
        for (int idx = tid; idx < 50 * 16; idx += 512) {
            int r = idx >> 4, g = idx & 15;
            int gp = p0 + r;
            float4 v = make_float4(0.f, 0.f, 0.f, 0.f);
            if (gp >= 0 && gp < 1920)
                v = *(const float4*)(x + (size_t)gp * 512 + kc * 64 + 4 * g);
            short* d = xs + r * 72 + 4 * g;
            d[0] = f2bf(v.x); d[1] = f2bf(v.y); d[2] = f2bf(v.z); d[3] = f2bf(v.w);
        }
        __syncthreads();

        #pragma unroll
        for (int ks = 0; ks < 10; ks++) {
            int kw  = ks >> 1;
            int ci0 = (ks & 1) * 32;
            short8 a = *(const short8*)(xs + (3 * mrow + kw) * 72 + ci0 + quad * 8);
            short8 b = *(const short8*)(w1s +
                ((((size_t)kc * 10 + ks) * 8 + w) * 64 + lane) * 8);
            acc = __builtin_amdgcn_mfma_f32_16x16x32_bf16(a, b, acc, 0, 0, 0);
        }
    }

    // epilogue: bias1, LN1 over 128 co (8 waves x 16 mrow), SiLU, bf16 store
    int co = w * 16 + mrow;
    float b1v = b1[co], g1v = g1[co], btv = bt1[co];

    float s1[4], s2[4];
    #pragma unroll
    for (int r = 0; r < 4; r++) {
        float v = acc[r] + b1v;
        acc[r] = v;
        s1[r] = v; s2[r] = v * v;
    }
    #pragma unroll
    for (int m = 8; m >= 1; m >>= 1) {
        #pragma unroll
        for (int r = 0; r < 4; r++) {
            s1[r] += __shfl_xor(s1[r], m, 64);
            s2[r] += __shfl_xor(s2[r], m, 64);
        }
    }
    if (mrow == 0) {
        #pragma unroll
        for (int r = 0; r < 4; r++) { red[w][quad][r][0] = s1[r]; red[w][quad][r][1] = s2[r]; }
    }
    __syncthreads();

    #pragma unroll
    for (int r = 0; r < 4; r++) {
        float S1 = 0.f, S2 = 0.f;
        #pragma unroll
        for (int ww = 0; ww < 8; ww++) {
            S1 += red[ww][quad][r][0];
            S2 += red[ww][quad][r][1];
        }
        float mean = S1 * (1.f / 128.f);
        float var  = S2 * (1.f / 128.f) - mean * mean;
        float rs   = rsqrtf(var + LN_EPS);
        int row = seq * 640 + tl * 16 + quad * 4 + r;
        float o = silu_f((acc[r] - mean) * rs * g1v + btv);
        h1[(size_t)row * 128 + co] = f2bf(o);
    }
}

// ---------------- Kernel 2: conv2 MFMA (16 pos x 1024 co) + LN2 + SiLU -> vp/sp
// grid = 40 blocks, 512 threads (8 waves x 8 n-tiles of 16 co each).
__global__ __launch_bounds__(512) void k_conv2m(
    const short* __restrict__ h1,    // (3200,128) bf16
    const short* __restrict__ w2s,
    const float* __restrict__ b2,
    const float* __restrict__ g2,
    const float* __restrict__ bt2,
    float* __restrict__ vp,          // (512,1024)
    float* __restrict__ sp)          // (128,1024)
{
    int blk  = blockIdx.x;           // 0..39
    int pos0 = blk * 16;
    int seq  = pos0 >> 7;
    int lcl0 = pos0 & 127;
    int row0 = seq * 640 + 5 * lcl0;

    __shared__ short xa[78 * 136];
    __shared__ float red[8][4][4][2];

    int tid = threadIdx.x;
    int lane = tid & 63, w = tid >> 6;
    int quad = lane >> 4, mrow = lane & 15;

    for (int idx = tid; idx < 78 * 16; idx += 512) {
        int r = idx >> 4, g = idx & 15;
        *(short8*)(xa + r * 136 + g * 8) =
            *(const short8*)(h1 + (size_t)(row0 + r) * 128 + g * 8);
    }
    __syncthreads();

    floatx4 acc[8];
    #pragma unroll
    for (int nt = 0; nt < 8; nt++) acc[nt] = (floatx4){0.f, 0.f, 0.f, 0.f};

    #pragma unroll 3
    for (int ks = 0; ks < 12; ks++) {
        int kw  = ks >> 2;
        int ci0 = (ks & 3) * 32;
        short8 a = *(const short8*)(xa + (5 * mrow + kw) * 136 + ci0 + quad * 8);
        #pragma unroll
        for (int nt = 0; nt < 8; nt++) {
            short8 b = *(const short8*)(w2s +
                (((size_t)ks * 64 + w * 8 + nt) * 64 + lane) * 8);
            acc[nt] = __builtin_amdgcn_mfma_f32_16x16x32_bf16(a, b, acc[nt], 0, 0, 0);
        }
    }

    float b2v[8], g2v[8], btv[8];
    #pragma unroll
    for (int nt = 0; nt < 8; nt++) {
        int co = (w * 8 + nt) * 16 + mrow;
        b2v[nt] = b2[co]; g2v[nt] = g2[co]; btv[nt] = bt2[co];
    }

    float s1[4] = {0.f, 0.f, 0.f, 0.f}, s2[4] = {0.f, 0.f, 0.f, 0.f};
    #pragma unroll
    for (int nt = 0; nt < 8; nt++)
        #pragma unroll
        for (int r = 0; r < 4; r++) {
            float v = acc[nt][r] + b2v[nt];
            acc[nt][r] = v;
            s1[r] += v; s2[r] += v * v;
        }
    #pragma unroll
    for (int m = 8; m >= 1; m >>= 1) {
        #pragma unroll
        for (int r = 0; r < 4; r++) {
            s1[r] += __shfl_xor(s1[r], m, 64);
            s2[r] += __shfl_xor(s2[r], m, 64);
        }
    }
    if (mrow == 0) {
        #pragma unroll
        for (int r = 0; r < 4; r++) { red[w][quad][r][0] = s1[r]; red[w][quad][r][1] = s2[r]; }
    }
    __syncthreads();

    float mean[4], rs[4];
    #pragma unroll
    for (int r = 0; r < 4; r++) {
        float S1 = 0.f, S2 = 0.f;
        #pragma unroll
        for (int ww = 0; ww < 8; ww++) {
            S1 += red[ww][quad][r][0];
            S2 += red[ww][quad][r][1];
        }
        mean[r] = S1 * (1.f / 1024.f);
        float var = S2 * (1.f / 1024.f) - mean[r] * mean[r];
        rs[r] = rsqrtf(var + LN_EPS);
    }

    float* obase = (pos0 < 512) ? (vp + (size_t)pos0 * 1024)
                                : (sp + (size_t)(pos0 - 512) * 1024);
    #pragma unroll
    for (int nt = 0; nt < 8; nt++) {
        int co = (w * 8 + nt) * 16 + mrow;
        #pragma unroll
        for (int r = 0; r < 4; r++) {
            float o = silu_f((acc[nt][r] - mean[r]) * rs[r] * g2v[nt] + btv[nt]);
            obase[((size_t)(quad * 4 + r)) * 1024 + co] = o;
        }
    }
}

// ---------------- Kernel 3: fused attention (counts + softmax + einsum + SiLU)
// grid = 4b * 64 jpair = 256 blocks, 512 threads (8 waves).
__global__ __launch_bounds__(512) void k_attn(
    const float* __restrict__ vp,   // (512,1024)
    const float* __restrict__ sp,   // (128,1024)
    float* __restrict__ O)          // (4,128,1024)
{
    int b  = blockIdx.x >> 6;
    int j0 = (blockIdx.x & 63) * 2;
    int tid = threadIdx.x, lane = tid & 63, wv = tid >> 6;

    __shared__ int   cc[4][128][2];
    __shared__ float sc0[128], sc1[128];
    __shared__ float redm[2][8], reds[2][8];

    // phase A: mismatch counts; thread = (i = tid&127, sub = tid>>7 covers 256 d)
    {
        int i = tid & 127, sub = tid >> 7;
        int d0 = sub * 256;
        const float* vrow = vp + ((size_t)(b * 128 + i)) * 1024 + d0;
        const float* s0r  = sp + (size_t)j0 * 1024 + d0;
        const float* s1r  = s0r + 1024;
        int m0 = 0, m1 = 0;
        #pragma unroll 8
        for (int k = 0; k < 64; k++) {
            float4 v  = *(const float4*)(vrow + 4 * k);
            float4 s0 = *(const float4*)(s0r + 4 * k);
            float4 s1 = *(const float4*)(s1r + 4 * k);
            m0 += mism1(v.x, s0.x) + mism1(v.y, s0.y) + mism1(v.z, s0.z) + mism1(v.w, s0.w);
            m1 += mism1(v.x, s1.x) + mism1(v.y, s1.y) + mism1(v.z, s1.z) + mism1(v.w, s1.w);
        }
        cc[sub][i][0] = m0;
        cc[sub][i][1] = m1;
    }
    __syncthreads();

    // phase B: softmax over i=128 for both j's (tid>=128 contribute neutrals)
    float S0v = -INFINITY, S1v = -INFINITY;
    if (tid < 128) {
        int c0 = cc[0][tid][0] + cc[1][tid][0] + cc[2][tid][0] + cc[3][tid][0];
        int c1 = cc[0][tid][1] + cc[1][tid][1] + cc[2][tid][1] + cc[3][tid][1];
        S0v = 1.f - (float)c0 * (2.f / 1024.f);
        S1v = 1.f - (float)c1 * (2.f / 1024.f);
    }
    float m0v = S0v, m1v = S1v;
    #pragma unroll
    for (int m = 32; m >= 1; m >>= 1) {
        m0v = fmaxf(m0v, __shfl_xor(m0v, m, 64));
        m1v = fmaxf(m1v, __shfl_xor(m1v, m, 64));
    }
    if (lane == 0) { redm[0][wv] = m0v; redm[1][wv] = m1v; }
    __syncthreads();
    float mx0 = -INFINITY, mx1 = -INFINITY;
    #pragma unroll
    for (int ww = 0; ww < 8; ww++) {
        mx0 = fmaxf(mx0, redm[0][ww]);
        mx1 = fmaxf(mx1, redm[1][ww]);
    }

    float e0 = (tid < 128) ? expf(S0v - mx0) : 0.f;
    float e1 = (tid < 128) ? expf(S1v - mx1) : 0.f;
    float t0 = e0, t1 = e1;
    #pragma unroll
    for (int m = 32; m >= 1; m >>= 1) {
        t0 += __shfl_xor(t0, m, 64);
        t1 += __shfl_xor(t1, m, 64);
    }
    if (lane == 0) { reds[0][wv] = t0; reds[1][wv] = t1; }
    __syncthreads();
    float tot0 = 0.f, tot1 = 0.f;
    #pragma unroll
    for (int ww = 0; ww < 8; ww++) { tot0 += reds[0][ww]; tot1 += reds[1][ww]; }
    if (tid < 128) { sc0[tid] = e0 / tot0; sc1[tid] = e1 / tot1; }
    __syncthreads();

    // phase C: einsum + SiLU; thread = (jj = tid>>8, dloc = tid&255)
    {
        int jj   = tid >> 8;
        int dloc = tid & 255;
        int dd   = 4 * dloc;
        int j    = j0 + jj;
        const float* scp = jj ? sc1 : sc0;

        const float* vpb = vp + (size_t)b * 131072;
        float4 ao = make_float4(0.f, 0.f, 0.f, 0.f);
        #pragma unroll 4
        for (int i = 0; i < 128; i++) {
            float4 v = *(const float4*)(vpb + (size_t)i * 1024 + dd);
            float f = scp[i];
            ao.x += f * v.x; ao.y += f * v.y; ao.z += f * v.z; ao.w += f * v.w;
        }
        float4 s = *(const float4*)(sp + (size_t)j * 1024 + dd);
        float4 o;
        o.x = silu_f(ao.x * s.x);
        o.y = silu_f(ao.y * s.y);
        o.z = silu_f(ao.z * s.z);
        o.w = silu_f(ao.w * s.w);
        *(float4*)(O + ((size_t)b * 128 + j) * 1024 + dd) = o;
    }
}

extern "C" void kernel_launch(void* const* d_in, const int* in_sizes, int n_in,
                              void* d_out, int out_size, void* d_ws, size_t ws_size,
                              hipStream_t stream) {
    const float* values  = (const float*)d_in[0];
    const float* symbols = (const float*)d_in[1];
    const float* conv1_w = (const float*)d_in[2];
    const float* conv1_b = (const float*)d_in[3];
    const float* ln1_g   = (const float*)d_in[4];
    const float* ln1_b   = (const float*)d_in[5];
    const float* conv2_w = (const float*)d_in[6];
    const float* conv2_b = (const float*)d_in[7];
    const float* ln2_g   = (const float*)d_in[8];
    const float* ln2_b   = (const float*)d_in[9];

    float* out = (float*)d_out;
    float* O   = out;                       // (4,128,1024)
    float* vp  = out + 4 * 128 * 1024;      // (4,128,1024)

    float* sp  = (float*)d_ws;              // (128,1024) f32
    short* h1  = (short*)(sp + 128 * 1024); // (3200,128) bf16
    short* w1s = h1 + 3200 * 128;           // 327,680
    short* w2s = w1s + 327680;              // 393,216

    k_prep<<<2816, 256, 0, stream>>>(conv1_w, conv2_w, w1s, w2s);
    k_conv1m<<<200, 512, 0, stream>>>(values, symbols, w1s,
                                      conv1_b, ln1_g, ln1_b, h1);
    k_conv2m<<<40, 512, 0, stream>>>(h1, w2s, conv2_b, ln2_g, ln2_b, vp, sp);
    k_attn<<<256, 512, 0, stream>>>(vp, sp, O);
}

// Round 13
// 172.043 us; speedup vs baseline: 4.6549x; 1.0845x over previous
//
#include <hip/hip_runtime.h>
#include <math.h>

#define LN_EPS 1e-3f

typedef __attribute__((ext_vector_type(8))) short short8;
typedef __attribute__((ext_vector_type(4))) float floatx4;

__device__ __forceinline__ float silu_f(float x) { return x / (1.f + expf(-x)); }

__device__ __forceinline__ int mism1(float a, float s) {
    unsigned ua = __float_as_uint(a);
    unsigned ub = __float_as_uint(a + s);
    return (int)((ua ^ ub) >> 31);
}

__device__ __forceinline__ short f2bf(float f) {
    unsigned u = __float_as_uint(f);
    unsigned r = (u + 0x7FFFu + ((u >> 16) & 1u)) >> 16;
    return (short)r;
}

// ---------------- Kernel 0: swizzle conv1 + conv2 weights into B-fragment bf16
// w1s[kc(8)][ks(10)][nt(8)][lane(64)][j(8)]  (327,680)
// w2s[ks(12)][nt(64)][lane(64)][j(8)]        (393,216)
__global__ __launch_bounds__(256) void k_prep(
    const float* __restrict__ w1,   // (5,512,128)
    const float* __restrict__ w2,   // (3,128,1024)
    short* __restrict__ w1s,
    short* __restrict__ w2s)
{
    int tid = blockIdx.x * 256 + threadIdx.x;
    if (tid < 327680) {
        int j    = tid & 7;
        int lane = (tid >> 3) & 63;
        int nt   = (tid >> 9) & 7;
        int ks   = (tid >> 12) % 10;
        int kc   = tid / 40960;
        int kw = ks >> 1;
        int ci = kc * 64 + (ks & 1) * 32 + ((lane >> 4) & 3) * 8 + j;
        int n  = nt * 16 + (lane & 15);
        w1s[tid] = f2bf(w1[((size_t)(kw * 512 + ci)) * 128 + n]);
    } else {
        int t = tid - 327680;
        if (t < 393216) {
            int j    = t & 7;
            int lane = (t >> 3) & 63;
            int nt   = (t >> 9) & 63;
            int ks   = t >> 15;                 // 0..11
            int k  = ks * 32 + ((lane >> 4) & 3) * 8 + j;   // 0..383
            int kw = k >> 7;
            int ci = k & 127;
            int n  = nt * 16 + (lane & 15);
            w2s[t] = f2bf(w2[((size_t)(kw * 128 + ci)) * 1024 + n]);
        }
    }
}

// ---------------- Kernel 1: conv1 MFMA + bias + LN1(128) + SiLU -> h1 bf16
// grid = 200 blocks (16 pos each), 256 threads (4 waves, 2 n-tiles each).
__global__ __launch_bounds__(256) void k_conv1m(
    const float* __restrict__ values,   // (4,1920,512)
    const float* __restrict__ symbols,  // (1920,512)
    const short* __restrict__ w1s,
    const float* __restrict__ b1,
    const float* __restrict__ g1,
    const float* __restrict__ bt1,
    short* __restrict__ h1)             // (3200,128) bf16
{
    int mt  = blockIdx.x;               // 0..199
    int seq = mt / 40;
    int tl  = mt % 40;
    const float* x = (seq < 4) ? (values + (size_t)seq * 1920 * 512) : symbols;
    int p0 = 3 * (tl * 16) - 1;

    __shared__ short xs[50 * 72];
    __shared__ float red[4][4][4][2];

    int tid  = threadIdx.x;
    int lane = tid & 63, w = tid >> 6;
    int quad = lane >> 4, mrow = lane & 15;

    floatx4 acc[2];
    acc[0] = (floatx4){0.f, 0.f, 0.f, 0.f};
    acc[1] = (floatx4){0.f, 0.f, 0.f, 0.f};

    for (int kc = 0; kc < 8; kc++) {
        __syncthreads();
        for (int idx = tid; idx < 50 * 16; idx += 256) {
            int r = idx >> 4, g = idx & 15;
            int gp = p0 + r;
            float4 v = make_float4(0.f, 0.f, 0.f, 0.f);
            if (gp >= 0 && gp < 1920)
                v = *(const float4*)(x + (size_t)gp * 512 + kc * 64 + 4 * g);
            short* d = xs + r * 72 + 4 * g;
            d[0] = f2bf(v.x); d[1] = f2bf(v.y); d[2] = f2bf(v.z); d[3] = f2bf(v.w);
        }
        __syncthreads();

        #pragma unroll
        for (int ks = 0; ks < 10; ks++) {
            int kw  = ks >> 1;
            int ci0 = (ks & 1) * 32;
            short8 a = *(const short8*)(xs + (3 * mrow + kw) * 72 + ci0 + quad * 8);
            #pragma unroll
            for (int ni = 0; ni < 2; ni++) {
                short8 b = *(const short8*)(w1s +
                    ((((size_t)kc * 10 + ks) * 8 + (w * 2 + ni)) * 64 + lane) * 8);
                acc[ni] = __builtin_amdgcn_mfma_f32_16x16x32_bf16(a, b, acc[ni], 0, 0, 0);
            }
        }
    }

    float b1v[2], g1v[2], btv[2];
    #pragma unroll
    for (int ni = 0; ni < 2; ni++) {
        int co = w * 32 + ni * 16 + mrow;
        b1v[ni] = b1[co]; g1v[ni] = g1[co]; btv[ni] = bt1[co];
    }

    float s1[4] = {0.f, 0.f, 0.f, 0.f}, s2[4] = {0.f, 0.f, 0.f, 0.f};
    #pragma unroll
    for (int ni = 0; ni < 2; ni++)
        #pragma unroll
        for (int r = 0; r < 4; r++) {
            float v = acc[ni][r] + b1v[ni];
            acc[ni][r] = v;
            s1[r] += v; s2[r] += v * v;
        }
    #pragma unroll
    for (int m = 8; m >= 1; m >>= 1) {
        #pragma unroll
        for (int r = 0; r < 4; r++) {
            s1[r] += __shfl_xor(s1[r], m, 64);
            s2[r] += __shfl_xor(s2[r], m, 64);
        }
    }
    if (mrow == 0) {
        #pragma unroll
        for (int r = 0; r < 4; r++) { red[w][quad][r][0] = s1[r]; red[w][quad][r][1] = s2[r]; }
    }
    __syncthreads();

    #pragma unroll
    for (int r = 0; r < 4; r++) {
        float S1 = red[0][quad][r][0] + red[1][quad][r][0]
                 + red[2][quad][r][0] + red[3][quad][r][0];
        float S2 = red[0][quad][r][1] + red[1][quad][r][1]
                 + red[2][quad][r][1] + red[3][quad][r][1];
        float mean = S1 * (1.f / 128.f);
        float var  = S2 * (1.f / 128.f) - mean * mean;
        float rs   = rsqrtf(var + LN_EPS);
        int row = seq * 640 + tl * 16 + quad * 4 + r;
        #pragma unroll
        for (int ni = 0; ni < 2; ni++) {
            float o = silu_f((acc[ni][r] - mean) * rs * g1v[ni] + btv[ni]);
            h1[(size_t)row * 128 + w * 32 + ni * 16 + mrow] = f2bf(o);
        }
    }
}

// ---------------- Kernel 2: conv2 MFMA (16 pos x 1024 co) + LN2 + SiLU -> vp/sp
// grid = 40 blocks, 256 threads (4 waves, 16 n-tiles each).
__global__ __launch_bounds__(256) void k_conv2m(
    const short* __restrict__ h1,    // (3200,128) bf16
    const short* __restrict__ w2s,
    const float* __restrict__ b2,
    const float* __restrict__ g2,
    const float* __restrict__ bt2,
    float* __restrict__ vp,          // (512,1024)
    float* __restrict__ sp)          // (128,1024)
{
    int blk  = blockIdx.x;           // 0..39
    int pos0 = blk * 16;
    int seq  = pos0 >> 7;
    int lcl0 = pos0 & 127;
    int row0 = seq * 640 + 5 * lcl0;

    __shared__ short xa[78 * 136];
    __shared__ float red[4][4][4][2];

    int tid = threadIdx.x;
    int lane = tid & 63, w = tid >> 6;
    int quad = lane >> 4, mrow = lane & 15;

    for (int idx = tid; idx < 78 * 16; idx += 256) {
        int r = idx >> 4, g = idx & 15;
        *(short8*)(xa + r * 136 + g * 8) =
            *(const short8*)(h1 + (size_t)(row0 + r) * 128 + g * 8);
    }
    __syncthreads();

    floatx4 acc[16];
    #pragma unroll
    for (int nt = 0; nt < 16; nt++) acc[nt] = (floatx4){0.f, 0.f, 0.f, 0.f};

    #pragma unroll 3
    for (int ks = 0; ks < 12; ks++) {
        int kw  = ks >> 2;
        int ci0 = (ks & 3) * 32;
        short8 a = *(const short8*)(xa + (5 * mrow + kw) * 136 + ci0 + quad * 8);
        #pragma unroll
        for (int nt = 0; nt < 16; nt++) {
            short8 b = *(const short8*)(w2s +
                (((size_t)ks * 64 + w * 16 + nt) * 64 + lane) * 8);
            acc[nt] = __builtin_amdgcn_mfma_f32_16x16x32_bf16(a, b, acc[nt], 0, 0, 0);
        }
    }

    float b2v[16], g2v[16], btv[16];
    #pragma unroll
    for (int nt = 0; nt < 16; nt++) {
        int co = w * 256 + nt * 16 + mrow;
        b2v[nt] = b2[co]; g2v[nt] = g2[co]; btv[nt] = bt2[co];
    }

    float s1[4] = {0.f, 0.f, 0.f, 0.f}, s2[4] = {0.f, 0.f, 0.f, 0.f};
    #pragma unroll
    for (int nt = 0; nt < 16; nt++)
        #pragma unroll
        for (int r = 0; r < 4; r++) {
            float v = acc[nt][r] + b2v[nt];
            acc[nt][r] = v;
            s1[r] += v; s2[r] += v * v;
        }
    #pragma unroll
    for (int m = 8; m >= 1; m >>= 1) {
        #pragma unroll
        for (int r = 0; r < 4; r++) {
            s1[r] += __shfl_xor(s1[r], m, 64);
            s2[r] += __shfl_xor(s2[r], m, 64);
        }
    }
    if (mrow == 0) {
        #pragma unroll
        for (int r = 0; r < 4; r++) { red[w][quad][r][0] = s1[r]; red[w][quad][r][1] = s2[r]; }
    }
    __syncthreads();

    float mean[4], rs[4];
    #pragma unroll
    for (int r = 0; r < 4; r++) {
        float S1 = red[0][quad][r][0] + red[1][quad][r][0]
                 + red[2][quad][r][0] + red[3][quad][r][0];
        float S2 = red[0][quad][r][1] + red[1][quad][r][1]
                 + red[2][quad][r][1] + red[3][quad][r][1];
        mean[r] = S1 * (1.f / 1024.f);
        float var = S2 * (1.f / 1024.f) - mean[r] * mean[r];
        rs[r] = rsqrtf(var + LN_EPS);
    }

    float* obase = (pos0 < 512) ? (vp + (size_t)pos0 * 1024)
                                : (sp + (size_t)(pos0 - 512) * 1024);
    #pragma unroll
    for (int nt = 0; nt < 16; nt++) {
        int co = w * 256 + nt * 16 + mrow;
        #pragma unroll
        for (int r = 0; r < 4; r++) {
            float o = silu_f((acc[nt][r] - mean[r]) * rs[r] * g2v[nt] + btv[nt]);
            obase[((size_t)(quad * 4 + r)) * 1024 + co] = o;
        }
    }
}

// ---------------- Kernel 3: fused attention (counts + softmax + einsum + SiLU)
// grid = 4b * 64 jpair = 256 blocks, 512 threads (8 waves).
// softmax: S in [-1,1] so exp(S) is safe without max subtraction.
__global__ __launch_bounds__(512) void k_attn(
    const float* __restrict__ vp,   // (512,1024)
    const float* __restrict__ sp,   // (128,1024)
    float* __restrict__ O)          // (4,128,1024)
{
    int b  = blockIdx.x >> 6;
    int j0 = (blockIdx.x & 63) * 2;
    int tid = threadIdx.x, lane = tid & 63, wv = tid >> 6;

    __shared__ int   cc[4][128][2];
    __shared__ float sc0[128], sc1[128];
    __shared__ float reds[2][8];

    // phase A: mismatch counts; thread = (i = tid&127, sub = tid>>7 covers 256 d)
    {
        int i = tid & 127, sub = tid >> 7;
        int d0 = sub * 256;
        const float* vrow = vp + ((size_t)(b * 128 + i)) * 1024 + d0;
        const float* s0r  = sp + (size_t)j0 * 1024 + d0;
        const float* s1r  = s0r + 1024;
        int m0 = 0, m1 = 0;
        #pragma unroll 8
        for (int k = 0; k < 64; k++) {
            float4 v  = *(const float4*)(vrow + 4 * k);
            float4 s0 = *(const float4*)(s0r + 4 * k);
            float4 s1 = *(const float4*)(s1r + 4 * k);
            m0 += mism1(v.x, s0.x) + mism1(v.y, s0.y) + mism1(v.z, s0.z) + mism1(v.w, s0.w);
            m1 += mism1(v.x, s1.x) + mism1(v.y, s1.y) + mism1(v.z, s1.z) + mism1(v.w, s1.w);
        }
        cc[sub][i][0] = m0;
        cc[sub][i][1] = m1;
    }
    __syncthreads();

    // phase B: softmax over i=128 for both j's, no max subtraction (S in [-1,1])
    float e0 = 0.f, e1 = 0.f;
    if (tid < 128) {
        int c0 = cc[0][tid][0] + cc[1][tid][0] + cc[2][tid][0] + cc[3][tid][0];
        int c1 = cc[0][tid][1] + cc[1][tid][1] + cc[2][tid][1] + cc[3][tid][1];
        e0 = expf(1.f - (float)c0 * (2.f / 1024.f));
        e1 = expf(1.f - (float)c1 * (2.f / 1024.f));
    }
    float t0 = e0, t1 = e1;
    #pragma unroll
    for (int m = 32; m >= 1; m >>= 1) {
        t0 += __shfl_xor(t0, m, 64);
        t1 += __shfl_xor(t1, m, 64);
    }
    if (lane == 0) { reds[0][wv] = t0; reds[1][wv] = t1; }
    __syncthreads();
    float tot0 = reds[0][0] + reds[0][1];
    float tot1 = reds[1][0] + reds[1][1];
    if (tid < 128) { sc0[tid] = e0 / tot0; sc1[tid] = e1 / tot1; }
    __syncthreads();

    // phase C: einsum + SiLU; thread = (jj = tid>>8, dloc = tid&255)
    {
        int jj   = tid >> 8;
        int dloc = tid & 255;
        int dd   = 4 * dloc;
        int j    = j0 + jj;
        const float* scp = jj ? sc1 : sc0;

        const float* vpb = vp + (size_t)b * 131072;
        float4 ao = make_float4(0.f, 0.f, 0.f, 0.f);
        #pragma unroll 4
        for (int i = 0; i < 128; i++) {
            float4 v = *(const float4*)(vpb + (size_t)i * 1024 + dd);
            float f = scp[i];
            ao.x += f * v.x; ao.y += f * v.y; ao.z += f * v.z; ao.w += f * v.w;
        }
        float4 s = *(const float4*)(sp + (size_t)j * 1024 + dd);
        float4 o;
        o.x = silu_f(ao.x * s.x);
        o.y = silu_f(ao.y * s.y);
        o.z = silu_f(ao.z * s.z);
        o.w = silu_f(ao.w * s.w);
        *(float4*)(O + ((size_t)b * 128 + j) * 1024 + dd) = o;
    }
}

extern "C" void kernel_launch(void* const* d_in, const int* in_sizes, int n_in,
                              void* d_out, int out_size, void* d_ws, size_t ws_size,
                              hipStream_t stream) {
    const float* values  = (const float*)d_in[0];
    const float* symbols = (const float*)d_in[1];
    const float* conv1_w = (const float*)d_in[2];
    const float* conv1_b = (const float*)d_in[3];
    const float* ln1_g   = (const float*)d_in[4];
    const float* ln1_b   = (const float*)d_in[5];
    const float* conv2_w = (const float*)d_in[6];
    const float* conv2_b = (const float*)d_in[7];
    const float* ln2_g   = (const float*)d_in[8];
    const float* ln2_b   = (const float*)d_in[9];

    float* out = (float*)d_out;
    float* O   = out;                       // (4,128,1024)
    float* vp  = out + 4 * 128 * 1024;      // (4,128,1024)

    float* sp  = (float*)d_ws;              // (128,1024) f32
    short* h1  = (short*)(sp + 128 * 1024); // (3200,128) bf16
    short* w1s = h1 + 3200 * 128;           // 327,680
    short* w2s = w1s + 327680;              // 393,216

    k_prep<<<2816, 256, 0, stream>>>(conv1_w, conv2_w, w1s, w2s);
    k_conv1m<<<200, 256, 0, stream>>>(values, symbols, w1s,
                                      conv1_b, ln1_g, ln1_b, h1);
    k_conv2m<<<40, 256, 0, stream>>>(h1, w2s, conv2_b, ln2_g, ln2_b, vp, sp);
    k_attn<<<256, 512, 0, stream>>>(vp, sp, O);
}